// Round 1
// baseline (186.515 us; speedup 1.0000x reference)
//
#include <hip/hip_runtime.h>

// Batched 1D linear interpolation with clamped extrapolation.
// t: [B,N] sorted fp32, v: [B,N] fp32, r: [B,M] fp32 -> out: [B,M] fp32
constexpr int B = 2048;
constexpr int N = 4096;
constexpr int M = 4096;

__global__ __launch_bounds__(256) void interp_kernel(
    const float* __restrict__ t,
    const float* __restrict__ v,
    const float* __restrict__ r,
    float* __restrict__ out) {
    __shared__ float st[N];
    __shared__ float sv[N];

    const int b = blockIdx.x;
    const float* tb = t + (size_t)b * N;
    const float* vb = v + (size_t)b * N;
    const float* rb = r + (size_t)b * M;
    float* ob = out + (size_t)b * M;

    // Stage t and v into LDS with coalesced float4 loads.
    const float4* t4 = (const float4*)tb;
    const float4* v4 = (const float4*)vb;
    float4* st4 = (float4*)st;
    float4* sv4 = (float4*)sv;
    for (int i = threadIdx.x; i < N / 4; i += blockDim.x) {
        st4[i] = t4[i];
        sv4[i] = v4[i];
    }
    __syncthreads();

    const float tfirst = st[0];
    const float tlast = st[N - 1];
    const float vfirst = sv[0];
    const float vlast = sv[N - 1];

    for (int m = threadIdx.x; m < M; m += blockDim.x) {
        const float q = rb[m];
        // Branchless binary search: lo = min(#elements <= q, N-1)
        // == clip(searchsorted(t, q, 'right'), 0, N-1) since steps sum to N-1.
        int lo = 0;
        #pragma unroll
        for (int step = N >> 1; step >= 1; step >>= 1) {
            const int cand = lo + step;
            lo = (st[cand - 1] <= q) ? cand : lo;
        }
        int idx = lo < 1 ? 1 : lo;  // upper bound already N-1
        const float t0 = st[idx - 1];
        const float t1 = st[idx];
        const float v0 = sv[idx - 1];
        const float v1 = sv[idx];
        const float denom = (t1 == t0) ? 1.0f : (t1 - t0);
        float o = v0 + (q - t0) / denom * (v1 - v0);
        o = (q < tfirst) ? vfirst : o;
        o = (q > tlast) ? vlast : o;
        ob[m] = o;
    }
}

extern "C" void kernel_launch(void* const* d_in, const int* in_sizes, int n_in,
                              void* d_out, int out_size, void* d_ws, size_t ws_size,
                              hipStream_t stream) {
    const float* t = (const float*)d_in[0];
    const float* v = (const float*)d_in[1];
    const float* r = (const float*)d_in[2];
    float* out = (float*)d_out;
    interp_kernel<<<B, 256, 0, stream>>>(t, v, r, out);
}

// Round 2
// 165.176 us; speedup vs baseline: 1.1292x; 1.1292x over previous
//
#include <hip/hip_runtime.h>

// Batched 1D linear interpolation with clamped extrapolation.
// t: [B,N] sorted fp32, v: [B,N] fp32, r: [B,M] fp32 -> out: [B,M] fp32
constexpr int B = 2048;
constexpr int N = 4096;
constexpr int M = 4096;

// XOR swizzle: bijection on [0,4096) that spreads the power-of-2-strided
// binary-search probe sets across banks. Without it, every probe address at
// level step=s (s>=16) is congruent mod 32 -> single-bank, up to 64-way
// serialized. With it, worst level is ~4-way.
__device__ __forceinline__ int swz(int i) { return i ^ ((i >> 5) & 31); }

__global__ __launch_bounds__(256) void interp_kernel(
    const float* __restrict__ t,
    const float* __restrict__ v,
    const float* __restrict__ r,
    float* __restrict__ out) {
    __shared__ float st[N];
    __shared__ float sv[N];

    const int b = blockIdx.x;
    const float* tb = t + (size_t)b * N;
    const float* vb = v + (size_t)b * N;
    const float* rb = r + (size_t)b * M;
    float* ob = out + (size_t)b * M;

    // Stage t and v into LDS at swizzled positions. Consecutive lanes within a
    // 32-group XOR by the same constant -> bank permutation -> conflict-free.
    for (int i = threadIdx.x; i < N; i += blockDim.x) {
        const int d = swz(i);
        st[d] = tb[i];
        sv[d] = vb[i];
    }
    __syncthreads();

    const float tfirst = st[swz(0)];
    const float tlast = st[swz(N - 1)];
    const float vfirst = sv[swz(0)];
    const float vlast = sv[swz(N - 1)];

    for (int m = threadIdx.x; m < M; m += blockDim.x) {
        const float q = rb[m];
        // Branchless binary search over swizzled LDS:
        // lo = min(#elements <= q, N-1) == clip(searchsorted(t,q,'right'),0,N-1)
        int lo = 0;
        #pragma unroll
        for (int step = N >> 1; step >= 1; step >>= 1) {
            const int cand = lo + step;
            lo = (st[swz(cand - 1)] <= q) ? cand : lo;
        }
        const int idx = lo < 1 ? 1 : lo;  // upper bound already N-1
        const float t0 = st[swz(idx - 1)];
        const float t1 = st[swz(idx)];
        const float v0 = sv[swz(idx - 1)];
        const float v1 = sv[swz(idx)];
        const float denom = (t1 == t0) ? 1.0f : (t1 - t0);
        float o = v0 + (q - t0) / denom * (v1 - v0);
        o = (q < tfirst) ? vfirst : o;
        o = (q > tlast) ? vlast : o;
        ob[m] = o;
    }
}

extern "C" void kernel_launch(void* const* d_in, const int* in_sizes, int n_in,
                              void* d_out, int out_size, void* d_ws, size_t ws_size,
                              hipStream_t stream) {
    const float* t = (const float*)d_in[0];
    const float* v = (const float*)d_in[1];
    const float* r = (const float*)d_in[2];
    float* out = (float*)d_out;
    interp_kernel<<<B, 256, 0, stream>>>(t, v, r, out);
}